// Round 3
// baseline (3071.600 us; speedup 1.0000x reference)
//
#include <hip/hip_runtime.h>

// ---------------------------------------------------------------------------
// GCN: CSR-by-dst build + 5 x (GEMM / gather-aggregate) + mean-pool + MLP.
// Neighbor tables stored bf16 (RNE), all accumulation and weights fp32.
// CSR fill uses atomicExch (memory-side 4B) to avoid 64B write-allocate.
// ---------------------------------------------------------------------------

static constexpr int TPB = 256;

__device__ __forceinline__ float u2f(unsigned u) { return __uint_as_float(u); }

// pack two fp32 -> two bf16 (RNE) in one uint
__device__ __forceinline__ unsigned bf2(float a, float b) {
    unsigned ua = __float_as_uint(a);
    unsigned ub = __float_as_uint(b);
    ua += 0x7FFFu + ((ua >> 16) & 1u);
    ub += 0x7FFFu + ((ub >> 16) & 1u);
    return (ua >> 16) | (ub & 0xFFFF0000u);
}

// ------------------------------- CSR build ---------------------------------
__global__ void k_count(const int* __restrict__ dst, int* __restrict__ cnt, int E) {
    int e = blockIdx.x * blockDim.x + threadIdx.x;
    if (e < E) atomicAdd(&cnt[dst[e]], 1);
}

__global__ void k_scanA(const int* __restrict__ cnt, int* __restrict__ rowptr,
                        int* __restrict__ bsum, int n) {
    __shared__ int s[TPB];
    int t = threadIdx.x;
    int i = blockIdx.x * TPB + t;
    s[t] = (i < n) ? cnt[i] : 0;
    __syncthreads();
    for (int off = 1; off < TPB; off <<= 1) {
        int add = (t >= off) ? s[t - off] : 0;
        __syncthreads();
        s[t] += add;
        __syncthreads();
    }
    if (i < n) rowptr[i + 1] = s[t];
    if (t == TPB - 1) bsum[blockIdx.x] = s[t];
}

__global__ void k_scanB(const int* __restrict__ bsum, int* __restrict__ bscan, int nb) {
    __shared__ int s[512];
    int t = threadIdx.x;
    s[t] = (t < nb) ? bsum[t] : 0;
    __syncthreads();
    for (int off = 1; off < 512; off <<= 1) {
        int add = (t >= off) ? s[t - off] : 0;
        __syncthreads();
        s[t] += add;
        __syncthreads();
    }
    if (t < nb) bscan[t] = (t > 0) ? s[t - 1] : 0;
}

// finalize rowptr, seed cursor = rowptr, compute dinv
__global__ void k_scanC(int* __restrict__ rowptr, int* __restrict__ cursor,
                        const int* __restrict__ bscan, const int* __restrict__ cnt,
                        float* __restrict__ dinv, int n) {
    int i = blockIdx.x * blockDim.x + threadIdx.x;
    if (i >= n) return;
    int v = rowptr[i + 1] + bscan[i >> 8];
    rowptr[i + 1] = v;
    if (i + 1 < n) cursor[i + 1] = v;
    dinv[i] = rsqrtf((float)cnt[i] + 1.0f);
    if (i == 0) { rowptr[0] = 0; cursor[0] = 0; }
}

__global__ void k_fill(const int* __restrict__ src, const int* __restrict__ dst,
                       int* __restrict__ cursor, int* __restrict__ csr, int E) {
    int e = blockIdx.x * blockDim.x + threadIdx.x;
    if (e >= E) return;
    int d = dst[e];
    int p = atomicAdd(&cursor[d], 1);
    atomicExch(&csr[p], src[e]);   // memory-side 4B write, no line write-allocate
}

// xs[i,k] = bf16(x[i,k] * dinv[i]); 8 elems/thread
__global__ void k_castx(const float* __restrict__ x, const float* __restrict__ dinv,
                        unsigned short* __restrict__ xs, int n) {
    int gid = blockIdx.x * blockDim.x + threadIdx.x;
    if (gid >= n * 8) return;
    int row = gid >> 3;
    float d = dinv[row];
    const float4* xp = (const float4*)x + (size_t)gid * 2;
    float4 a = xp[0], b = xp[1];
    uint4 o;
    o.x = bf2(a.x * d, a.y * d);
    o.y = bf2(a.z * d, a.w * d);
    o.z = bf2(b.x * d, b.y * d);
    o.w = bf2(b.z * d, b.w * d);
    ((uint4*)xs)[gid] = o;
}

// ------------------------------- GEMM --------------------------------------
// EPI 0: out = bf16(acc * dinv[row])            (feeds gather)
// EPI 1: out = fp32 relu(acc + bias)            (layer-1 output)
template <int K, int OUT, int EPI>
__global__ __launch_bounds__(256) void k_gemm(const float* __restrict__ xin,
                                              const float* __restrict__ W,
                                              const float* __restrict__ dinv,
                                              const float* __restrict__ bias,
                                              void* __restrict__ outp, int n) {
    constexpr int CG = OUT / 16;           // threads spanning OUT (16 cols each)
    constexpr int R = (OUT <= 32) ? 2 : 8; // rows per thread
    constexpr int ROWS = (256 / CG) * R;   // rows per block
    constexpr int KC = 32;                 // K chunk staged in LDS
    constexpr int QS = OUT / 4;            // col-quad stride (conflict-free)
    __shared__ float Wl[KC * OUT];

    int t = threadIdx.x;
    int cg = t % CG;
    int rl = t / CG;
    int r0 = blockIdx.x * ROWS + rl * R;

    float acc[R][16];
#pragma unroll
    for (int r = 0; r < R; ++r)
#pragma unroll
        for (int c = 0; c < 16; ++c) acc[r][c] = 0.f;

    const float4* W4 = (const float4*)W;
    const float4* xb = (const float4*)(xin + (size_t)r0 * K);
    const bool full = (r0 + R <= n);

    for (int kc = 0; kc < K / KC; ++kc) {
        __syncthreads();
        for (int i = t; i < KC * OUT / 4; i += 256)
            ((float4*)Wl)[i] = W4[kc * (KC * OUT / 4) + i];
        __syncthreads();
#pragma unroll
        for (int k4 = 0; k4 < KC / 4; ++k4) {
            float4 xr[R];
            if (full) {
#pragma unroll
                for (int r = 0; r < R; ++r)
                    xr[r] = xb[r * (K / 4) + kc * (KC / 4) + k4];
            } else {
#pragma unroll
                for (int r = 0; r < R; ++r) {
                    int rr = r0 + r;
                    const float4* xp =
                        (const float4*)(xin + (size_t)(rr < n ? rr : (n - 1)) * K);
                    xr[r] = xp[kc * (KC / 4) + k4];
                }
            }
#pragma unroll
            for (int u = 0; u < 4; ++u) {
                float4 wq[4];
#pragma unroll
                for (int q = 0; q < 4; ++q)
                    wq[q] = *(const float4*)&Wl[(k4 * 4 + u) * OUT + cg * 4 + q * QS];
#pragma unroll
                for (int r = 0; r < R; ++r) {
                    float a = (u == 0) ? xr[r].x : (u == 1) ? xr[r].y
                                                : (u == 2) ? xr[r].z : xr[r].w;
#pragma unroll
                    for (int q = 0; q < 4; ++q) {
                        acc[r][q * 4 + 0] += a * wq[q].x;
                        acc[r][q * 4 + 1] += a * wq[q].y;
                        acc[r][q * 4 + 2] += a * wq[q].z;
                        acc[r][q * 4 + 3] += a * wq[q].w;
                    }
                }
            }
        }
    }

    if (EPI == 0) {
        unsigned short* ob = (unsigned short*)outp;
#pragma unroll
        for (int r = 0; r < R; ++r) {
            int rr = r0 + r;
            if (!full && rr >= n) continue;
            float d = dinv[rr];
#pragma unroll
            for (int q = 0; q < 4; ++q) {
                uint2 p;
                p.x = bf2(acc[r][q * 4 + 0] * d, acc[r][q * 4 + 1] * d);
                p.y = bf2(acc[r][q * 4 + 2] * d, acc[r][q * 4 + 3] * d);
                *(uint2*)(ob + (size_t)rr * OUT + cg * 4 + q * QS) = p;
            }
        }
    } else {
        float* of = (float*)outp;
        float4 bq[4];
#pragma unroll
        for (int q = 0; q < 4; ++q) bq[q] = *(const float4*)&bias[cg * 4 + q * QS];
#pragma unroll
        for (int r = 0; r < R; ++r) {
            int rr = r0 + r;
            if (!full && rr >= n) continue;
#pragma unroll
            for (int q = 0; q < 4; ++q) {
                float4 v;
                v.x = fmaxf(acc[r][q * 4 + 0] + bq[q].x, 0.f);
                v.y = fmaxf(acc[r][q * 4 + 1] + bq[q].y, 0.f);
                v.z = fmaxf(acc[r][q * 4 + 2] + bq[q].z, 0.f);
                v.w = fmaxf(acc[r][q * 4 + 3] + bq[q].w, 0.f);
                *(float4*)&of[(size_t)rr * OUT + cg * 4 + q * QS] = v;
            }
        }
    }
}

// --------------------------- gather (bf16 table) ---------------------------
__device__ __forceinline__ void addbf(float* acc, uint4 w) {
    acc[0] += u2f(w.x << 16); acc[1] += u2f(w.x & 0xFFFF0000u);
    acc[2] += u2f(w.y << 16); acc[3] += u2f(w.y & 0xFFFF0000u);
    acc[4] += u2f(w.z << 16); acc[5] += u2f(w.z & 0xFFFF0000u);
    acc[6] += u2f(w.w << 16); acc[7] += u2f(w.w & 0xFFFF0000u);
}

// out_i = [relu]( dinv_i * (hs_i + sum_j hs_j) [+ bias] )   fp32 out
template <int D, bool RELU, bool HASBIAS>
__global__ __launch_bounds__(256) void k_gather_bf(const unsigned short* __restrict__ hsb,
                                                   const int* __restrict__ rowptr,
                                                   const int* __restrict__ csr,
                                                   const float* __restrict__ dinv,
                                                   const float* __restrict__ bias,
                                                   float* __restrict__ out, int n) {
    constexpr int TPN = D / 8;  // threads per node, 8 bf16 (16B) each
    int gid = blockIdx.x * blockDim.x + threadIdx.x;
    int node = gid / TPN;
    if (node >= n) return;
    int c = gid % TPN;
    const uint4* hb = (const uint4*)hsb;

    float acc[8];
    {
        uint4 v = hb[(size_t)node * TPN + c];
        acc[0] = u2f(v.x << 16); acc[1] = u2f(v.x & 0xFFFF0000u);
        acc[2] = u2f(v.y << 16); acc[3] = u2f(v.y & 0xFFFF0000u);
        acc[4] = u2f(v.z << 16); acc[5] = u2f(v.z & 0xFFFF0000u);
        acc[6] = u2f(v.w << 16); acc[7] = u2f(v.w & 0xFFFF0000u);
    }
    int j0 = rowptr[node], j1 = rowptr[node + 1];
    int j = j0;
    for (; j + 3 < j1; j += 4) {  // unroll-4 for memory-level parallelism
        int s0 = csr[j], s1 = csr[j + 1], s2 = csr[j + 2], s3 = csr[j + 3];
        uint4 w0 = hb[(size_t)s0 * TPN + c];
        uint4 w1 = hb[(size_t)s1 * TPN + c];
        uint4 w2 = hb[(size_t)s2 * TPN + c];
        uint4 w3 = hb[(size_t)s3 * TPN + c];
        addbf(acc, w0); addbf(acc, w1); addbf(acc, w2); addbf(acc, w3);
    }
    for (; j < j1; ++j) {
        uint4 w0 = hb[(size_t)csr[j] * TPN + c];
        addbf(acc, w0);
    }

    float di = dinv[node];
    float r[8];
    if (HASBIAS) {
        float4 b0 = *(const float4*)&bias[c * 8];
        float4 b1 = *(const float4*)&bias[c * 8 + 4];
        r[0] = di * acc[0] + b0.x; r[1] = di * acc[1] + b0.y;
        r[2] = di * acc[2] + b0.z; r[3] = di * acc[3] + b0.w;
        r[4] = di * acc[4] + b1.x; r[5] = di * acc[5] + b1.y;
        r[6] = di * acc[6] + b1.z; r[7] = di * acc[7] + b1.w;
    } else {
#pragma unroll
        for (int i = 0; i < 8; ++i) r[i] = di * acc[i];
    }
    if (RELU) {
#pragma unroll
        for (int i = 0; i < 8; ++i) r[i] = fmaxf(r[i], 0.f);
    }
    float4 o0 = {r[0], r[1], r[2], r[3]};
    float4 o1 = {r[4], r[5], r[6], r[7]};
    float4* op = (float4*)(out + (size_t)node * D + c * 8);
    op[0] = o0;
    op[1] = o1;
}

// ------------------------------ pool + MLP ---------------------------------
__global__ __launch_bounds__(256) void k_pool(const float* __restrict__ h,
                                              const int* __restrict__ batch,
                                              float* __restrict__ g, int n) {
    __shared__ int se[2];
    __shared__ float red[8][32];
    int gi = blockIdx.x;
    int t = threadIdx.x;
    if (t == 0) {
        int lo = 0, hi = n;
        while (lo < hi) { int m = (lo + hi) >> 1; if (batch[m] < gi) lo = m + 1; else hi = m; }
        se[0] = lo;
        lo = 0; hi = n;
        while (lo < hi) { int m = (lo + hi) >> 1; if (batch[m] < gi + 1) lo = m + 1; else hi = m; }
        se[1] = lo;
    }
    __syncthreads();
    int start = se[0], end = se[1];
    int col = t & 31, sub = t >> 5;
    float acc = 0.f;
    for (int i = start + sub; i < end; i += 8)
        acc += h[(size_t)i * 32 + col];
    red[sub][col] = acc;
    __syncthreads();
    if (t < 32) {
        float s = 0.f;
#pragma unroll
        for (int q = 0; q < 8; ++q) s += red[q][t];
        float c = (float)(end - start);
        g[gi * 32 + t] = s / fmaxf(c, 1.0f);
    }
}

template <int K, int O, bool RELU>
__global__ void k_mlp(const float* __restrict__ in, const float* __restrict__ W,
                      const float* __restrict__ b, float* __restrict__ out, int G) {
    int gid = blockIdx.x * blockDim.x + threadIdx.x;
    if (gid >= G * O) return;
    int g = gid / O, j = gid % O;
    float s = b[j];
    for (int k = 0; k < K; ++k) s += in[g * K + k] * W[k * O + j];
    if (RELU) s = fmaxf(s, 0.f);
    out[gid] = s;
}

// ------------------------------- launch ------------------------------------
extern "C" void kernel_launch(void* const* d_in, const int* in_sizes, int n_in,
                              void* d_out, int out_size, void* d_ws, size_t ws_size,
                              hipStream_t stream) {
    const float* x    = (const float*)d_in[0];
    const int*   ei   = (const int*)d_in[1];
    const int*   batch= (const int*)d_in[2];
    const float* W1 = (const float*)d_in[3];  const float* b1 = (const float*)d_in[4];
    const float* W2 = (const float*)d_in[5];  const float* b2 = (const float*)d_in[6];
    const float* W3 = (const float*)d_in[7];  const float* b3 = (const float*)d_in[8];
    const float* W4 = (const float*)d_in[9];  const float* b4 = (const float*)d_in[10];
    const float* Wo = (const float*)d_in[11]; const float* bo = (const float*)d_in[12];
    const float* M1w = (const float*)d_in[13]; const float* M1b = (const float*)d_in[14];
    const float* M2w = (const float*)d_in[15]; const float* M2b = (const float*)d_in[16];
    const float* M3w = (const float*)d_in[17]; const float* M3b = (const float*)d_in[18];

    const int N = in_sizes[0] / 64;   // 100000
    const int E = in_sizes[1] / 2;    // 1600000
    const int G = out_size / 8;       // 64
    const int* src  = ei;
    const int* dstp = ei + E;

    // workspace layout (aliased where lifetimes are disjoint)
    char* w = (char*)d_ws;
    float* A   = (float*)w;                    // N*128 fp32 (activations)
    unsigned short* xs = (unsigned short*)w;   //   aliased: N*64 bf16 (layer-1 input)
    w += (size_t)N * 128 * 4;
    float* agg = (float*)w;                    // N*64 fp32 (layer-1 agg)
    unsigned short* hsb = (unsigned short*)w;  //   aliased: N*128 bf16 (tables)
    w += (size_t)N * 128 * 2;
    int*   csr    = (int*)w;   w += (size_t)E * 4;
    int*   cnt    = (int*)w;   w += (size_t)N * 4;
    int*   rowptr = (int*)w;   w += (size_t)(N + 4) * 4;
    int*   cursor = (int*)w;   w += (size_t)N * 4;
    int*   bsum   = (int*)w;   w += 4096;
    int*   bscan  = (int*)w;   w += 4096;
    float* dinv   = (float*)w; w += (size_t)N * 4;
    float* gp     = (float*)w; w += 64 * 32 * 4;
    float* m1     = (float*)w; w += 64 * 64 * 4;
    float* m2     = (float*)w; w += 64 * 16 * 4;

    const int NB = (N + TPB - 1) / TPB;
    const int EB = (E + TPB - 1) / TPB;

    hipMemsetAsync(cnt, 0, (size_t)N * 4, stream);
    k_count<<<EB, TPB, 0, stream>>>(dstp, cnt, E);
    k_scanA<<<NB, TPB, 0, stream>>>(cnt, rowptr, bsum, N);
    k_scanB<<<1, 512, 0, stream>>>(bsum, bscan, NB);
    k_scanC<<<NB, TPB, 0, stream>>>(rowptr, cursor, bscan, cnt, dinv, N);
    k_fill<<<EB, TPB, 0, stream>>>(src, dstp, cursor, csr, E);

    // Layer 1 (aggregate-first on 64-dim): xs = bf16(x*dinv); agg = dinv*(sum);
    // A = relu(agg@W1 + b1)
    k_castx<<<(N * 8 + 255) / 256, 256, 0, stream>>>(x, dinv, xs, N);
    k_gather_bf<64, false, false><<<(N * 8 + 255) / 256, 256, 0, stream>>>(
        xs, rowptr, csr, dinv, nullptr, agg, N);
    k_gemm<64, 128, 1><<<(N + 255) / 256, 256, 0, stream>>>(agg, W1, nullptr, b1, A, N);

    // Layers 2-4: hsb = bf16((A@W)*dinv); A = relu(dinv*(gather) + b)
    k_gemm<128, 128, 0><<<(N + 255) / 256, 256, 0, stream>>>(A, W2, dinv, nullptr, hsb, N);
    k_gather_bf<128, true, true><<<(N * 16 + 255) / 256, 256, 0, stream>>>(
        hsb, rowptr, csr, dinv, b2, A, N);
    k_gemm<128, 128, 0><<<(N + 255) / 256, 256, 0, stream>>>(A, W3, dinv, nullptr, hsb, N);
    k_gather_bf<128, true, true><<<(N * 16 + 255) / 256, 256, 0, stream>>>(
        hsb, rowptr, csr, dinv, b3, A, N);
    k_gemm<128, 128, 0><<<(N + 255) / 256, 256, 0, stream>>>(A, W4, dinv, nullptr, hsb, N);
    k_gather_bf<128, true, true><<<(N * 16 + 255) / 256, 256, 0, stream>>>(
        hsb, rowptr, csr, dinv, b4, A, N);

    // Layer 5: 128 -> 32, no relu
    k_gemm<128, 32, 0><<<(N + 255) / 256, 256, 0, stream>>>(A, Wo, dinv, nullptr, hsb, N);
    k_gather_bf<32, false, true><<<(N * 4 + 255) / 256, 256, 0, stream>>>(
        hsb, rowptr, csr, dinv, bo, A, N);

    // Mean pool + MLP head
    k_pool<<<G, 256, 0, stream>>>(A, batch, gp, N);
    k_mlp<32, 64, true><<<(G * 64 + 255) / 256, 256, 0, stream>>>(gp, M1w, M1b, m1, G);
    k_mlp<64, 16, true><<<(G * 16 + 255) / 256, 256, 0, stream>>>(m1, M2w, M2b, m2, G);
    k_mlp<16, 8, false><<<(G * 8 + 255) / 256, 256, 0, stream>>>(m2, M3w, M3b, (float*)d_out, G);
}

// Round 4
// 899.048 us; speedup vs baseline: 3.4165x; 3.4165x over previous
//
#include <hip/hip_runtime.h>

// ---------------------------------------------------------------------------
// GCN: CSR-by-dst build + 5 x (GEMM / gather-aggregate) + mean-pool + MLP.
// Neighbor tables stored bf16 (RNE), all accumulation and weights fp32.
// CSR fill uses atomicExch (memory-side 4B) to avoid 64B write-allocate.
// GEMM: R=4 rows/thread (R=8 spilled: 256 VGPR cap -> 1.8GB scratch traffic).
// ---------------------------------------------------------------------------

static constexpr int TPB = 256;

__device__ __forceinline__ float u2f(unsigned u) { return __uint_as_float(u); }

// pack two fp32 -> two bf16 (RNE) in one uint
__device__ __forceinline__ unsigned bf2(float a, float b) {
    unsigned ua = __float_as_uint(a);
    unsigned ub = __float_as_uint(b);
    ua += 0x7FFFu + ((ua >> 16) & 1u);
    ub += 0x7FFFu + ((ub >> 16) & 1u);
    return (ua >> 16) | (ub & 0xFFFF0000u);
}

// ------------------------------- CSR build ---------------------------------
__global__ void k_count(const int* __restrict__ dst, int* __restrict__ cnt, int E) {
    int e = blockIdx.x * blockDim.x + threadIdx.x;
    if (e < E) atomicAdd(&cnt[dst[e]], 1);
}

__global__ void k_scanA(const int* __restrict__ cnt, int* __restrict__ rowptr,
                        int* __restrict__ bsum, int n) {
    __shared__ int s[TPB];
    int t = threadIdx.x;
    int i = blockIdx.x * TPB + t;
    s[t] = (i < n) ? cnt[i] : 0;
    __syncthreads();
    for (int off = 1; off < TPB; off <<= 1) {
        int add = (t >= off) ? s[t - off] : 0;
        __syncthreads();
        s[t] += add;
        __syncthreads();
    }
    if (i < n) rowptr[i + 1] = s[t];
    if (t == TPB - 1) bsum[blockIdx.x] = s[t];
}

__global__ void k_scanB(const int* __restrict__ bsum, int* __restrict__ bscan, int nb) {
    __shared__ int s[512];
    int t = threadIdx.x;
    s[t] = (t < nb) ? bsum[t] : 0;
    __syncthreads();
    for (int off = 1; off < 512; off <<= 1) {
        int add = (t >= off) ? s[t - off] : 0;
        __syncthreads();
        s[t] += add;
        __syncthreads();
    }
    if (t < nb) bscan[t] = (t > 0) ? s[t - 1] : 0;
}

// finalize rowptr, seed cursor = rowptr, compute dinv
__global__ void k_scanC(int* __restrict__ rowptr, int* __restrict__ cursor,
                        const int* __restrict__ bscan, const int* __restrict__ cnt,
                        float* __restrict__ dinv, int n) {
    int i = blockIdx.x * blockDim.x + threadIdx.x;
    if (i >= n) return;
    int v = rowptr[i + 1] + bscan[i >> 8];
    rowptr[i + 1] = v;
    if (i + 1 < n) cursor[i + 1] = v;
    dinv[i] = rsqrtf((float)cnt[i] + 1.0f);
    if (i == 0) { rowptr[0] = 0; cursor[0] = 0; }
}

__global__ void k_fill(const int* __restrict__ src, const int* __restrict__ dst,
                       int* __restrict__ cursor, int* __restrict__ csr, int E) {
    int e = blockIdx.x * blockDim.x + threadIdx.x;
    if (e >= E) return;
    int d = dst[e];
    int p = atomicAdd(&cursor[d], 1);
    atomicExch(&csr[p], src[e]);   // memory-side 4B write, no line write-allocate
}

// xs[i,k] = bf16(x[i,k] * dinv[i]); 8 elems/thread
__global__ void k_castx(const float* __restrict__ x, const float* __restrict__ dinv,
                        unsigned short* __restrict__ xs, int n) {
    int gid = blockIdx.x * blockDim.x + threadIdx.x;
    if (gid >= n * 8) return;
    int row = gid >> 3;
    float d = dinv[row];
    const float4* xp = (const float4*)x + (size_t)gid * 2;
    float4 a = xp[0], b = xp[1];
    uint4 o;
    o.x = bf2(a.x * d, a.y * d);
    o.y = bf2(a.z * d, a.w * d);
    o.z = bf2(b.x * d, b.y * d);
    o.w = bf2(b.z * d, b.w * d);
    ((uint4*)xs)[gid] = o;
}

// ------------------------------- GEMM --------------------------------------
// EPI 0: out = bf16(acc * dinv[row])            (feeds gather)
// EPI 1: out = fp32 relu(acc + bias)            (layer-1 output)
template <int K, int OUT, int EPI>
__global__ __launch_bounds__(256) void k_gemm(const float* __restrict__ xin,
                                              const float* __restrict__ W,
                                              const float* __restrict__ dinv,
                                              const float* __restrict__ bias,
                                              void* __restrict__ outp, int n) {
    constexpr int CG = OUT / 16;           // threads spanning OUT (16 cols each)
    constexpr int R = (OUT <= 32) ? 2 : 4; // rows per thread (R=8 spills!)
    constexpr int ROWS = (256 / CG) * R;   // rows per block
    constexpr int KC = 32;                 // K chunk staged in LDS
    constexpr int QS = OUT / 4;            // col-quad stride (conflict-free)
    __shared__ float Wl[KC * OUT];

    int t = threadIdx.x;
    int cg = t % CG;
    int rl = t / CG;
    int r0 = blockIdx.x * ROWS + rl * R;

    float acc[R][16];
#pragma unroll
    for (int r = 0; r < R; ++r)
#pragma unroll
        for (int c = 0; c < 16; ++c) acc[r][c] = 0.f;

    const float4* W4 = (const float4*)W;
    const float4* xp[R];
    int rows[R];
    bool val[R];
#pragma unroll
    for (int r = 0; r < R; ++r) {
        rows[r] = r0 + r;
        val[r] = rows[r] < n;
        int rr = val[r] ? rows[r] : (n - 1);
        xp[r] = (const float4*)(xin + (size_t)rr * K);
    }

    for (int kc = 0; kc < K / KC; ++kc) {
        __syncthreads();
        for (int i = t; i < KC * OUT / 4; i += 256)
            ((float4*)Wl)[i] = W4[kc * (KC * OUT / 4) + i];
        __syncthreads();
#pragma unroll
        for (int k4 = 0; k4 < KC / 4; ++k4) {
            float4 xr[R];
#pragma unroll
            for (int r = 0; r < R; ++r) xr[r] = xp[r][kc * (KC / 4) + k4];
#pragma unroll
            for (int u = 0; u < 4; ++u) {
                float4 wq[4];
#pragma unroll
                for (int q = 0; q < 4; ++q)
                    wq[q] = *(const float4*)&Wl[(k4 * 4 + u) * OUT + cg * 4 + q * QS];
#pragma unroll
                for (int r = 0; r < R; ++r) {
                    float a = (u == 0) ? xr[r].x : (u == 1) ? xr[r].y
                                                : (u == 2) ? xr[r].z : xr[r].w;
#pragma unroll
                    for (int q = 0; q < 4; ++q) {
                        acc[r][q * 4 + 0] += a * wq[q].x;
                        acc[r][q * 4 + 1] += a * wq[q].y;
                        acc[r][q * 4 + 2] += a * wq[q].z;
                        acc[r][q * 4 + 3] += a * wq[q].w;
                    }
                }
            }
        }
    }

    if (EPI == 0) {
        unsigned short* ob = (unsigned short*)outp;
#pragma unroll
        for (int r = 0; r < R; ++r) {
            if (!val[r]) continue;
            float d = dinv[rows[r]];
#pragma unroll
            for (int q = 0; q < 4; ++q) {
                uint2 p;
                p.x = bf2(acc[r][q * 4 + 0] * d, acc[r][q * 4 + 1] * d);
                p.y = bf2(acc[r][q * 4 + 2] * d, acc[r][q * 4 + 3] * d);
                *(uint2*)(ob + (size_t)rows[r] * OUT + cg * 4 + q * QS) = p;
            }
        }
    } else {
        float* of = (float*)outp;
        float4 bq[4];
#pragma unroll
        for (int q = 0; q < 4; ++q) bq[q] = *(const float4*)&bias[cg * 4 + q * QS];
#pragma unroll
        for (int r = 0; r < R; ++r) {
            if (!val[r]) continue;
#pragma unroll
            for (int q = 0; q < 4; ++q) {
                float4 v;
                v.x = fmaxf(acc[r][q * 4 + 0] + bq[q].x, 0.f);
                v.y = fmaxf(acc[r][q * 4 + 1] + bq[q].y, 0.f);
                v.z = fmaxf(acc[r][q * 4 + 2] + bq[q].z, 0.f);
                v.w = fmaxf(acc[r][q * 4 + 3] + bq[q].w, 0.f);
                *(float4*)&of[(size_t)rows[r] * OUT + cg * 4 + q * QS] = v;
            }
        }
    }
}

// --------------------------- gather (bf16 table) ---------------------------
__device__ __forceinline__ void addbf(float* acc, uint4 w) {
    acc[0] += u2f(w.x << 16); acc[1] += u2f(w.x & 0xFFFF0000u);
    acc[2] += u2f(w.y << 16); acc[3] += u2f(w.y & 0xFFFF0000u);
    acc[4] += u2f(w.z << 16); acc[5] += u2f(w.z & 0xFFFF0000u);
    acc[6] += u2f(w.w << 16); acc[7] += u2f(w.w & 0xFFFF0000u);
}

// out_i = [relu]( dinv_i * (hs_i + sum_j hs_j) [+ bias] )   fp32 out
template <int D, bool RELU, bool HASBIAS>
__global__ __launch_bounds__(256) void k_gather_bf(const unsigned short* __restrict__ hsb,
                                                   const int* __restrict__ rowptr,
                                                   const int* __restrict__ csr,
                                                   const float* __restrict__ dinv,
                                                   const float* __restrict__ bias,
                                                   float* __restrict__ out, int n) {
    constexpr int TPN = D / 8;  // threads per node, 8 bf16 (16B) each
    int gid = blockIdx.x * blockDim.x + threadIdx.x;
    int node = gid / TPN;
    if (node >= n) return;
    int c = gid % TPN;
    const uint4* hb = (const uint4*)hsb;

    float acc[8];
    {
        uint4 v = hb[(size_t)node * TPN + c];
        acc[0] = u2f(v.x << 16); acc[1] = u2f(v.x & 0xFFFF0000u);
        acc[2] = u2f(v.y << 16); acc[3] = u2f(v.y & 0xFFFF0000u);
        acc[4] = u2f(v.z << 16); acc[5] = u2f(v.z & 0xFFFF0000u);
        acc[6] = u2f(v.w << 16); acc[7] = u2f(v.w & 0xFFFF0000u);
    }
    int j0 = rowptr[node], j1 = rowptr[node + 1];
    int j = j0;
    for (; j + 3 < j1; j += 4) {  // unroll-4 for memory-level parallelism
        int s0 = csr[j], s1 = csr[j + 1], s2 = csr[j + 2], s3 = csr[j + 3];
        uint4 w0 = hb[(size_t)s0 * TPN + c];
        uint4 w1 = hb[(size_t)s1 * TPN + c];
        uint4 w2 = hb[(size_t)s2 * TPN + c];
        uint4 w3 = hb[(size_t)s3 * TPN + c];
        addbf(acc, w0); addbf(acc, w1); addbf(acc, w2); addbf(acc, w3);
    }
    for (; j < j1; ++j) {
        uint4 w0 = hb[(size_t)csr[j] * TPN + c];
        addbf(acc, w0);
    }

    float di = dinv[node];
    float r[8];
    if (HASBIAS) {
        float4 b0 = *(const float4*)&bias[c * 8];
        float4 b1 = *(const float4*)&bias[c * 8 + 4];
        r[0] = di * acc[0] + b0.x; r[1] = di * acc[1] + b0.y;
        r[2] = di * acc[2] + b0.z; r[3] = di * acc[3] + b0.w;
        r[4] = di * acc[4] + b1.x; r[5] = di * acc[5] + b1.y;
        r[6] = di * acc[6] + b1.z; r[7] = di * acc[7] + b1.w;
    } else {
#pragma unroll
        for (int i = 0; i < 8; ++i) r[i] = di * acc[i];
    }
    if (RELU) {
#pragma unroll
        for (int i = 0; i < 8; ++i) r[i] = fmaxf(r[i], 0.f);
    }
    float4 o0 = {r[0], r[1], r[2], r[3]};
    float4 o1 = {r[4], r[5], r[6], r[7]};
    float4* op = (float4*)(out + (size_t)node * D + c * 8);
    op[0] = o0;
    op[1] = o1;
}

// ------------------------------ pool + MLP ---------------------------------
__global__ __launch_bounds__(256) void k_pool(const float* __restrict__ h,
                                              const int* __restrict__ batch,
                                              float* __restrict__ g, int n) {
    __shared__ int se[2];
    __shared__ float red[8][32];
    int gi = blockIdx.x;
    int t = threadIdx.x;
    if (t == 0) {
        int lo = 0, hi = n;
        while (lo < hi) { int m = (lo + hi) >> 1; if (batch[m] < gi) lo = m + 1; else hi = m; }
        se[0] = lo;
        lo = 0; hi = n;
        while (lo < hi) { int m = (lo + hi) >> 1; if (batch[m] < gi + 1) lo = m + 1; else hi = m; }
        se[1] = lo;
    }
    __syncthreads();
    int start = se[0], end = se[1];
    int col = t & 31, sub = t >> 5;
    float acc = 0.f;
    for (int i = start + sub; i < end; i += 8)
        acc += h[(size_t)i * 32 + col];
    red[sub][col] = acc;
    __syncthreads();
    if (t < 32) {
        float s = 0.f;
#pragma unroll
        for (int q = 0; q < 8; ++q) s += red[q][t];
        float c = (float)(end - start);
        g[gi * 32 + t] = s / fmaxf(c, 1.0f);
    }
}

template <int K, int O, bool RELU>
__global__ void k_mlp(const float* __restrict__ in, const float* __restrict__ W,
                      const float* __restrict__ b, float* __restrict__ out, int G) {
    int gid = blockIdx.x * blockDim.x + threadIdx.x;
    if (gid >= G * O) return;
    int g = gid / O, j = gid % O;
    float s = b[j];
    for (int k = 0; k < K; ++k) s += in[g * K + k] * W[k * O + j];
    if (RELU) s = fmaxf(s, 0.f);
    out[gid] = s;
}

// ------------------------------- launch ------------------------------------
extern "C" void kernel_launch(void* const* d_in, const int* in_sizes, int n_in,
                              void* d_out, int out_size, void* d_ws, size_t ws_size,
                              hipStream_t stream) {
    const float* x    = (const float*)d_in[0];
    const int*   ei   = (const int*)d_in[1];
    const int*   batch= (const int*)d_in[2];
    const float* W1 = (const float*)d_in[3];  const float* b1 = (const float*)d_in[4];
    const float* W2 = (const float*)d_in[5];  const float* b2 = (const float*)d_in[6];
    const float* W3 = (const float*)d_in[7];  const float* b3 = (const float*)d_in[8];
    const float* W4 = (const float*)d_in[9];  const float* b4 = (const float*)d_in[10];
    const float* Wo = (const float*)d_in[11]; const float* bo = (const float*)d_in[12];
    const float* M1w = (const float*)d_in[13]; const float* M1b = (const float*)d_in[14];
    const float* M2w = (const float*)d_in[15]; const float* M2b = (const float*)d_in[16];
    const float* M3w = (const float*)d_in[17]; const float* M3b = (const float*)d_in[18];

    const int N = in_sizes[0] / 64;   // 100000
    const int E = in_sizes[1] / 2;    // 1600000
    const int G = out_size / 8;       // 64
    const int* src  = ei;
    const int* dstp = ei + E;

    // workspace layout (aliased where lifetimes are disjoint)
    char* w = (char*)d_ws;
    float* A   = (float*)w;                    // N*128 fp32 (activations)
    unsigned short* xs = (unsigned short*)w;   //   aliased: N*64 bf16 (layer-1 input)
    w += (size_t)N * 128 * 4;
    float* agg = (float*)w;                    // N*64 fp32 (layer-1 agg)
    unsigned short* hsb = (unsigned short*)w;  //   aliased: N*128 bf16 (tables)
    w += (size_t)N * 128 * 2;
    int*   csr    = (int*)w;   w += (size_t)E * 4;
    int*   cnt    = (int*)w;   w += (size_t)N * 4;
    int*   rowptr = (int*)w;   w += (size_t)(N + 4) * 4;
    int*   cursor = (int*)w;   w += (size_t)N * 4;
    int*   bsum   = (int*)w;   w += 4096;
    int*   bscan  = (int*)w;   w += 4096;
    float* dinv   = (float*)w; w += (size_t)N * 4;
    float* gp     = (float*)w; w += 64 * 32 * 4;
    float* m1     = (float*)w; w += 64 * 64 * 4;
    float* m2     = (float*)w; w += 64 * 16 * 4;

    const int NB = (N + TPB - 1) / TPB;
    const int EB = (E + TPB - 1) / TPB;

    hipMemsetAsync(cnt, 0, (size_t)N * 4, stream);
    k_count<<<EB, TPB, 0, stream>>>(dstp, cnt, E);
    k_scanA<<<NB, TPB, 0, stream>>>(cnt, rowptr, bsum, N);
    k_scanB<<<1, 512, 0, stream>>>(bsum, bscan, NB);
    k_scanC<<<NB, TPB, 0, stream>>>(rowptr, cursor, bscan, cnt, dinv, N);
    k_fill<<<EB, TPB, 0, stream>>>(src, dstp, cursor, csr, E);

    // Layer 1 (aggregate-first on 64-dim): xs = bf16(x*dinv); agg = dinv*(sum);
    // A = relu(agg@W1 + b1)
    k_castx<<<(N * 8 + 255) / 256, 256, 0, stream>>>(x, dinv, xs, N);
    k_gather_bf<64, false, false><<<(N * 8 + 255) / 256, 256, 0, stream>>>(
        xs, rowptr, csr, dinv, nullptr, agg, N);
    k_gemm<64, 128, 1><<<(N + 127) / 128, 256, 0, stream>>>(agg, W1, nullptr, b1, A, N);

    // Layers 2-4: hsb = bf16((A@W)*dinv); A = relu(dinv*(gather) + b)
    k_gemm<128, 128, 0><<<(N + 127) / 128, 256, 0, stream>>>(A, W2, dinv, nullptr, hsb, N);
    k_gather_bf<128, true, true><<<(N * 16 + 255) / 256, 256, 0, stream>>>(
        hsb, rowptr, csr, dinv, b2, A, N);
    k_gemm<128, 128, 0><<<(N + 127) / 128, 256, 0, stream>>>(A, W3, dinv, nullptr, hsb, N);
    k_gather_bf<128, true, true><<<(N * 16 + 255) / 256, 256, 0, stream>>>(
        hsb, rowptr, csr, dinv, b3, A, N);
    k_gemm<128, 128, 0><<<(N + 127) / 128, 256, 0, stream>>>(A, W4, dinv, nullptr, hsb, N);
    k_gather_bf<128, true, true><<<(N * 16 + 255) / 256, 256, 0, stream>>>(
        hsb, rowptr, csr, dinv, b4, A, N);

    // Layer 5: 128 -> 32, no relu
    k_gemm<128, 32, 0><<<(N + 255) / 256, 256, 0, stream>>>(A, Wo, dinv, nullptr, hsb, N);
    k_gather_bf<32, false, true><<<(N * 4 + 255) / 256, 256, 0, stream>>>(
        hsb, rowptr, csr, dinv, bo, A, N);

    // Mean pool + MLP head
    k_pool<<<G, 256, 0, stream>>>(A, batch, gp, N);
    k_mlp<32, 64, true><<<(G * 64 + 255) / 256, 256, 0, stream>>>(gp, M1w, M1b, m1, G);
    k_mlp<64, 16, true><<<(G * 16 + 255) / 256, 256, 0, stream>>>(m1, M2w, M2b, m2, G);
    k_mlp<16, 8, false><<<(G * 8 + 255) / 256, 256, 0, stream>>>(m2, M3w, M3b, (float*)d_out, G);
}

// Round 5
// 770.686 us; speedup vs baseline: 3.9855x; 1.1666x over previous
//
#include <hip/hip_runtime.h>

// ---------------------------------------------------------------------------
// GCN: bucketed CSR-by-dst build + 5 x (GEMM / gather-aggregate) + pool + MLP.
// Neighbor tables stored bf16 (RNE), all accumulation and weights fp32.
// CSR build: histogram -> bucket-major staging (packed uint) -> LDS-cursor
// scatter, so all random writes land in L2-local regions (random 4B scatter
// costs 64B/edge at HBM otherwise -- measured 100MB writes in r2-r4).
// GEMM: R=4 rows/thread (R=8 spilled: 256 VGPR cap -> 1.8GB scratch traffic).
// ---------------------------------------------------------------------------

static constexpr int TPB = 256;
static constexpr int NBKT = 128;   // dst buckets: bucket = dst >> 10
static constexpr int NCHK = 256;   // edge chunks

__device__ __forceinline__ float u2f(unsigned u) { return __uint_as_float(u); }

// pack two fp32 -> two bf16 (RNE) in one uint
__device__ __forceinline__ unsigned bf2(float a, float b) {
    unsigned ua = __float_as_uint(a);
    unsigned ub = __float_as_uint(b);
    ua += 0x7FFFu + ((ua >> 16) & 1u);
    ub += 0x7FFFu + ((ub >> 16) & 1u);
    return (ua >> 16) | (ub & 0xFFFF0000u);
}

// ------------------------------- CSR build ---------------------------------
// 1) per-chunk LDS histogram over dst buckets
__global__ __launch_bounds__(256) void k_hist(const int* __restrict__ dst,
                                              int* __restrict__ histT, int E, int CS) {
    __shared__ int h[NBKT];
    int c = blockIdx.x, t = threadIdx.x;
    if (t < NBKT) h[t] = 0;
    __syncthreads();
    int e0 = c * CS, e1 = min(e0 + CS, E);
    for (int e = e0 + t; e < e1; e += 256)
        atomicAdd(&h[dst[e] >> 10], 1);
    __syncthreads();
    if (t < NBKT) histT[t * NCHK + c] = h[t];
}

// 2) exclusive scan of NBKT*NCHK cells (lexicographic r,c) -> staging offsets
__global__ __launch_bounds__(256) void k_scanS(const int* __restrict__ histT,
                                               int* __restrict__ stg) {
    constexpr int TOT = NBKT * NCHK;
    constexpr int PER = TOT / 256;
    __shared__ int s[256];
    int t = threadIdx.x;
    int base = t * PER;
    int sum = 0;
    for (int i = 0; i < PER; ++i) sum += histT[base + i];
    s[t] = sum;
    __syncthreads();
    for (int off = 1; off < 256; off <<= 1) {
        int add = (t >= off) ? s[t - off] : 0;
        __syncthreads();
        s[t] += add;
        __syncthreads();
    }
    int run = (t > 0) ? s[t - 1] : 0;
    for (int i = 0; i < PER; ++i) {
        stg[base + i] = run;
        run += histT[base + i];
    }
}

// 3) scatter edges into bucket-major staging, packed (src<<10)|dst_lo
__global__ __launch_bounds__(256) void k_bucket(const int* __restrict__ src,
                                                const int* __restrict__ dst,
                                                const int* __restrict__ stg,
                                                unsigned* __restrict__ staging,
                                                int E, int CS) {
    __shared__ int cur[NBKT];
    int c = blockIdx.x, t = threadIdx.x;
    if (t < NBKT) cur[t] = stg[t * NCHK + c];
    __syncthreads();
    int e0 = c * CS, e1 = min(e0 + CS, E);
    for (int e = e0 + t; e < e1; e += 256) {
        int d = dst[e];
        int p = atomicAdd(&cur[d >> 10], 1);
        staging[p] = ((unsigned)src[e] << 10) | (unsigned)(d & 1023);
    }
}

// 4) per-bucket degree count via LDS
__global__ __launch_bounds__(256) void k_deg(const unsigned* __restrict__ staging,
                                             const int* __restrict__ stg,
                                             int* __restrict__ cnt, int E, int n) {
    __shared__ int deg[1024];
    int r = blockIdx.x, t = threadIdx.x;
    for (int i = t; i < 1024; i += 256) deg[i] = 0;
    __syncthreads();
    int s0 = stg[r * NCHK];
    int s1 = (r == NBKT - 1) ? E : stg[(r + 1) * NCHK];
    for (int e = s0 + t; e < s1; e += 256)
        atomicAdd(&deg[staging[e] & 1023u], 1);
    __syncthreads();
    int b = r << 10;
    for (int i = t; i < 1024; i += 256)
        if (b + i < n) cnt[b + i] = deg[i];
}

// rowptr scan over cnt (3 kernels) + dinv
__global__ void k_scanA(const int* __restrict__ cnt, int* __restrict__ rowptr,
                        int* __restrict__ bsum, int n) {
    __shared__ int s[TPB];
    int t = threadIdx.x;
    int i = blockIdx.x * TPB + t;
    s[t] = (i < n) ? cnt[i] : 0;
    __syncthreads();
    for (int off = 1; off < TPB; off <<= 1) {
        int add = (t >= off) ? s[t - off] : 0;
        __syncthreads();
        s[t] += add;
        __syncthreads();
    }
    if (i < n) rowptr[i + 1] = s[t];
    if (t == TPB - 1) bsum[blockIdx.x] = s[t];
}

__global__ void k_scanB(const int* __restrict__ bsum, int* __restrict__ bscan, int nb) {
    __shared__ int s[512];
    int t = threadIdx.x;
    s[t] = (t < nb) ? bsum[t] : 0;
    __syncthreads();
    for (int off = 1; off < 512; off <<= 1) {
        int add = (t >= off) ? s[t - off] : 0;
        __syncthreads();
        s[t] += add;
        __syncthreads();
    }
    if (t < nb) bscan[t] = (t > 0) ? s[t - 1] : 0;
}

__global__ void k_scanC(int* __restrict__ rowptr, const int* __restrict__ bscan,
                        const int* __restrict__ cnt, float* __restrict__ dinv, int n) {
    int i = blockIdx.x * blockDim.x + threadIdx.x;
    if (i >= n) return;
    rowptr[i + 1] += bscan[i >> 8];
    dinv[i] = rsqrtf((float)cnt[i] + 1.0f);
    if (i == 0) rowptr[0] = 0;
}

// 5) final scatter: LDS cursors, csr writes stay in one contiguous L2 region
__global__ __launch_bounds__(256) void k_fill2(const unsigned* __restrict__ staging,
                                               const int* __restrict__ stg,
                                               const int* __restrict__ rowptr,
                                               int* __restrict__ csr, int E, int n) {
    __shared__ int cur[1024];
    int r = blockIdx.x, t = threadIdx.x;
    int b = r << 10;
    for (int i = t; i < 1024; i += 256)
        cur[i] = (b + i < n) ? rowptr[b + i] : 0;
    __syncthreads();
    int s0 = stg[r * NCHK];
    int s1 = (r == NBKT - 1) ? E : stg[(r + 1) * NCHK];
    for (int e = s0 + t; e < s1; e += 256) {
        unsigned sd = staging[e];
        int p = atomicAdd(&cur[sd & 1023u], 1);
        csr[p] = (int)(sd >> 10);
    }
}

// xs[i,k] = bf16(x[i,k] * dinv[i]); 8 elems/thread
__global__ void k_castx(const float* __restrict__ x, const float* __restrict__ dinv,
                        unsigned short* __restrict__ xs, int n) {
    int gid = blockIdx.x * blockDim.x + threadIdx.x;
    if (gid >= n * 8) return;
    int row = gid >> 3;
    float d = dinv[row];
    const float4* xp = (const float4*)x + (size_t)gid * 2;
    float4 a = xp[0], b = xp[1];
    uint4 o;
    o.x = bf2(a.x * d, a.y * d);
    o.y = bf2(a.z * d, a.w * d);
    o.z = bf2(b.x * d, b.y * d);
    o.w = bf2(b.z * d, b.w * d);
    ((uint4*)xs)[gid] = o;
}

// ------------------------------- GEMM --------------------------------------
// EPI 0: out = bf16(acc * dinv[row])            (feeds gather)
// EPI 1: out = fp32 relu(acc + bias)            (layer-1 output)
template <int K, int OUT, int EPI>
__global__ __launch_bounds__(256) void k_gemm(const float* __restrict__ xin,
                                              const float* __restrict__ W,
                                              const float* __restrict__ dinv,
                                              const float* __restrict__ bias,
                                              void* __restrict__ outp, int n) {
    constexpr int CG = OUT / 16;           // threads spanning OUT (16 cols each)
    constexpr int R = (OUT <= 32) ? 2 : 4; // rows per thread (R=8 spills!)
    constexpr int ROWS = (256 / CG) * R;   // rows per block
    constexpr int KC = 32;                 // K chunk staged in LDS
    constexpr int QS = OUT / 4;            // col-quad stride (conflict-free)
    __shared__ float Wl[KC * OUT];

    int t = threadIdx.x;
    int cg = t % CG;
    int rl = t / CG;
    int r0 = blockIdx.x * ROWS + rl * R;

    float acc[R][16];
#pragma unroll
    for (int r = 0; r < R; ++r)
#pragma unroll
        for (int c = 0; c < 16; ++c) acc[r][c] = 0.f;

    const float4* W4 = (const float4*)W;
    const float4* xp[R];
    int rows[R];
    bool val[R];
#pragma unroll
    for (int r = 0; r < R; ++r) {
        rows[r] = r0 + r;
        val[r] = rows[r] < n;
        int rr = val[r] ? rows[r] : (n - 1);
        xp[r] = (const float4*)(xin + (size_t)rr * K);
    }

    for (int kc = 0; kc < K / KC; ++kc) {
        __syncthreads();
        for (int i = t; i < KC * OUT / 4; i += 256)
            ((float4*)Wl)[i] = W4[kc * (KC * OUT / 4) + i];
        __syncthreads();
#pragma unroll
        for (int k4 = 0; k4 < KC / 4; ++k4) {
            float4 xr[R];
#pragma unroll
            for (int r = 0; r < R; ++r) xr[r] = xp[r][kc * (KC / 4) + k4];
#pragma unroll
            for (int u = 0; u < 4; ++u) {
                float4 wq[4];
#pragma unroll
                for (int q = 0; q < 4; ++q)
                    wq[q] = *(const float4*)&Wl[(k4 * 4 + u) * OUT + cg * 4 + q * QS];
#pragma unroll
                for (int r = 0; r < R; ++r) {
                    float a = (u == 0) ? xr[r].x : (u == 1) ? xr[r].y
                                                : (u == 2) ? xr[r].z : xr[r].w;
#pragma unroll
                    for (int q = 0; q < 4; ++q) {
                        acc[r][q * 4 + 0] += a * wq[q].x;
                        acc[r][q * 4 + 1] += a * wq[q].y;
                        acc[r][q * 4 + 2] += a * wq[q].z;
                        acc[r][q * 4 + 3] += a * wq[q].w;
                    }
                }
            }
        }
    }

    if (EPI == 0) {
        unsigned short* ob = (unsigned short*)outp;
#pragma unroll
        for (int r = 0; r < R; ++r) {
            if (!val[r]) continue;
            float d = dinv[rows[r]];
#pragma unroll
            for (int q = 0; q < 4; ++q) {
                uint2 p;
                p.x = bf2(acc[r][q * 4 + 0] * d, acc[r][q * 4 + 1] * d);
                p.y = bf2(acc[r][q * 4 + 2] * d, acc[r][q * 4 + 3] * d);
                *(uint2*)(ob + (size_t)rows[r] * OUT + cg * 4 + q * QS) = p;
            }
        }
    } else {
        float* of = (float*)outp;
        float4 bq[4];
#pragma unroll
        for (int q = 0; q < 4; ++q) bq[q] = *(const float4*)&bias[cg * 4 + q * QS];
#pragma unroll
        for (int r = 0; r < R; ++r) {
            if (!val[r]) continue;
#pragma unroll
            for (int q = 0; q < 4; ++q) {
                float4 v;
                v.x = fmaxf(acc[r][q * 4 + 0] + bq[q].x, 0.f);
                v.y = fmaxf(acc[r][q * 4 + 1] + bq[q].y, 0.f);
                v.z = fmaxf(acc[r][q * 4 + 2] + bq[q].z, 0.f);
                v.w = fmaxf(acc[r][q * 4 + 3] + bq[q].w, 0.f);
                *(float4*)&of[(size_t)rows[r] * OUT + cg * 4 + q * QS] = v;
            }
        }
    }
}

// --------------------------- gather (bf16 table) ---------------------------
__device__ __forceinline__ void addbf(float* acc, uint4 w) {
    acc[0] += u2f(w.x << 16); acc[1] += u2f(w.x & 0xFFFF0000u);
    acc[2] += u2f(w.y << 16); acc[3] += u2f(w.y & 0xFFFF0000u);
    acc[4] += u2f(w.z << 16); acc[5] += u2f(w.z & 0xFFFF0000u);
    acc[6] += u2f(w.w << 16); acc[7] += u2f(w.w & 0xFFFF0000u);
}

// out_i = [relu]( dinv_i * (hs_i + sum_j hs_j) [+ bias] )   fp32 out
template <int D, bool RELU, bool HASBIAS>
__global__ __launch_bounds__(256) void k_gather_bf(const unsigned short* __restrict__ hsb,
                                                   const int* __restrict__ rowptr,
                                                   const int* __restrict__ csr,
                                                   const float* __restrict__ dinv,
                                                   const float* __restrict__ bias,
                                                   float* __restrict__ out, int n) {
    constexpr int TPN = D / 8;  // threads per node, 8 bf16 (16B) each
    int gid = blockIdx.x * blockDim.x + threadIdx.x;
    int node = gid / TPN;
    if (node >= n) return;
    int c = gid % TPN;
    const uint4* hb = (const uint4*)hsb;

    float acc[8];
    {
        uint4 v = hb[(size_t)node * TPN + c];
        acc[0] = u2f(v.x << 16); acc[1] = u2f(v.x & 0xFFFF0000u);
        acc[2] = u2f(v.y << 16); acc[3] = u2f(v.y & 0xFFFF0000u);
        acc[4] = u2f(v.z << 16); acc[5] = u2f(v.z & 0xFFFF0000u);
        acc[6] = u2f(v.w << 16); acc[7] = u2f(v.w & 0xFFFF0000u);
    }
    int j0 = rowptr[node], j1 = rowptr[node + 1];
    int j = j0;
    for (; j + 3 < j1; j += 4) {  // unroll-4 for memory-level parallelism
        int s0 = csr[j], s1 = csr[j + 1], s2 = csr[j + 2], s3 = csr[j + 3];
        uint4 w0 = hb[(size_t)s0 * TPN + c];
        uint4 w1 = hb[(size_t)s1 * TPN + c];
        uint4 w2 = hb[(size_t)s2 * TPN + c];
        uint4 w3 = hb[(size_t)s3 * TPN + c];
        addbf(acc, w0); addbf(acc, w1); addbf(acc, w2); addbf(acc, w3);
    }
    for (; j < j1; ++j) {
        uint4 w0 = hb[(size_t)csr[j] * TPN + c];
        addbf(acc, w0);
    }

    float di = dinv[node];
    float r[8];
    if (HASBIAS) {
        float4 b0 = *(const float4*)&bias[c * 8];
        float4 b1 = *(const float4*)&bias[c * 8 + 4];
        r[0] = di * acc[0] + b0.x; r[1] = di * acc[1] + b0.y;
        r[2] = di * acc[2] + b0.z; r[3] = di * acc[3] + b0.w;
        r[4] = di * acc[4] + b1.x; r[5] = di * acc[5] + b1.y;
        r[6] = di * acc[6] + b1.z; r[7] = di * acc[7] + b1.w;
    } else {
#pragma unroll
        for (int i = 0; i < 8; ++i) r[i] = di * acc[i];
    }
    if (RELU) {
#pragma unroll
        for (int i = 0; i < 8; ++i) r[i] = fmaxf(r[i], 0.f);
    }
    float4 o0 = {r[0], r[1], r[2], r[3]};
    float4 o1 = {r[4], r[5], r[6], r[7]};
    float4* op = (float4*)(out + (size_t)node * D + c * 8);
    op[0] = o0;
    op[1] = o1;
}

// ------------------------------ pool + MLP ---------------------------------
__global__ __launch_bounds__(256) void k_pool(const float* __restrict__ h,
                                              const int* __restrict__ batch,
                                              float* __restrict__ g, int n) {
    __shared__ int se[2];
    __shared__ float red[8][32];
    int gi = blockIdx.x;
    int t = threadIdx.x;
    if (t == 0) {
        int lo = 0, hi = n;
        while (lo < hi) { int m = (lo + hi) >> 1; if (batch[m] < gi) lo = m + 1; else hi = m; }
        se[0] = lo;
        lo = 0; hi = n;
        while (lo < hi) { int m = (lo + hi) >> 1; if (batch[m] < gi + 1) lo = m + 1; else hi = m; }
        se[1] = lo;
    }
    __syncthreads();
    int start = se[0], end = se[1];
    int col = t & 31, sub = t >> 5;
    float acc = 0.f;
    for (int i = start + sub; i < end; i += 8)
        acc += h[(size_t)i * 32 + col];
    red[sub][col] = acc;
    __syncthreads();
    if (t < 32) {
        float s = 0.f;
#pragma unroll
        for (int q = 0; q < 8; ++q) s += red[q][t];
        float c = (float)(end - start);
        g[gi * 32 + t] = s / fmaxf(c, 1.0f);
    }
}

template <int K, int O, bool RELU>
__global__ void k_mlp(const float* __restrict__ in, const float* __restrict__ W,
                      const float* __restrict__ b, float* __restrict__ out, int G) {
    int gid = blockIdx.x * blockDim.x + threadIdx.x;
    if (gid >= G * O) return;
    int g = gid / O, j = gid % O;
    float s = b[j];
    for (int k = 0; k < K; ++k) s += in[g * K + k] * W[k * O + j];
    if (RELU) s = fmaxf(s, 0.f);
    out[gid] = s;
}

// ------------------------------- launch ------------------------------------
extern "C" void kernel_launch(void* const* d_in, const int* in_sizes, int n_in,
                              void* d_out, int out_size, void* d_ws, size_t ws_size,
                              hipStream_t stream) {
    const float* x    = (const float*)d_in[0];
    const int*   ei   = (const int*)d_in[1];
    const int*   batch= (const int*)d_in[2];
    const float* W1 = (const float*)d_in[3];  const float* b1 = (const float*)d_in[4];
    const float* W2 = (const float*)d_in[5];  const float* b2 = (const float*)d_in[6];
    const float* W3 = (const float*)d_in[7];  const float* b3 = (const float*)d_in[8];
    const float* W4 = (const float*)d_in[9];  const float* b4 = (const float*)d_in[10];
    const float* Wo = (const float*)d_in[11]; const float* bo = (const float*)d_in[12];
    const float* M1w = (const float*)d_in[13]; const float* M1b = (const float*)d_in[14];
    const float* M2w = (const float*)d_in[15]; const float* M2b = (const float*)d_in[16];
    const float* M3w = (const float*)d_in[17]; const float* M3b = (const float*)d_in[18];

    const int N = in_sizes[0] / 64;   // 100000
    const int E = in_sizes[1] / 2;    // 1600000
    const int G = out_size / 8;       // 64
    const int* src  = ei;
    const int* dstp = ei + E;

    // workspace layout (aliased where lifetimes are disjoint)
    char* w = (char*)d_ws;
    float* A   = (float*)w;                    // N*128 fp32 (activations)
    unsigned short* xs = (unsigned short*)w;   //   aliased: N*64 bf16 (layer-1 input)
    w += (size_t)N * 128 * 4;
    float* agg = (float*)w;                    // N*64 fp32 (layer-1 agg)
    unsigned short* hsb = (unsigned short*)w;  //   aliased: N*128 bf16 (tables)
    w += (size_t)N * 128 * 2;
    int*      csr     = (int*)w;      w += (size_t)E * 4;
    unsigned* staging = (unsigned*)w; w += (size_t)E * 4;
    int*      histT   = (int*)w;      w += NBKT * NCHK * 4;
    int*      stg     = (int*)w;      w += NBKT * NCHK * 4;
    int*      cnt     = (int*)w;      w += (size_t)N * 4;
    int*      rowptr  = (int*)w;      w += (size_t)(N + 4) * 4;
    int*      bsum    = (int*)w;      w += 4096;
    int*      bscan   = (int*)w;      w += 4096;
    float*    dinv    = (float*)w;    w += (size_t)N * 4;
    float*    gp      = (float*)w;    w += 64 * 32 * 4;
    float*    m1      = (float*)w;    w += 64 * 64 * 4;
    float*    m2      = (float*)w;    w += 64 * 16 * 4;

    const int NB = (N + TPB - 1) / TPB;
    const int CS = (E + NCHK - 1) / NCHK;

    // ---- CSR build (bucketed; no memory-side random scatter) ----
    k_hist<<<NCHK, 256, 0, stream>>>(dstp, histT, E, CS);
    k_scanS<<<1, 256, 0, stream>>>(histT, stg);
    k_bucket<<<NCHK, 256, 0, stream>>>(src, dstp, stg, staging, E, CS);
    k_deg<<<NBKT, 256, 0, stream>>>(staging, stg, cnt, E, N);
    k_scanA<<<NB, TPB, 0, stream>>>(cnt, rowptr, bsum, N);
    k_scanB<<<1, 512, 0, stream>>>(bsum, bscan, NB);
    k_scanC<<<NB, TPB, 0, stream>>>(rowptr, bscan, cnt, dinv, N);
    k_fill2<<<NBKT, 256, 0, stream>>>(staging, stg, rowptr, csr, E, N);

    // Layer 1 (aggregate-first on 64-dim): xs = bf16(x*dinv); agg = dinv*(sum);
    // A = relu(agg@W1 + b1)
    k_castx<<<(N * 8 + 255) / 256, 256, 0, stream>>>(x, dinv, xs, N);
    k_gather_bf<64, false, false><<<(N * 8 + 255) / 256, 256, 0, stream>>>(
        xs, rowptr, csr, dinv, nullptr, agg, N);
    k_gemm<64, 128, 1><<<(N + 127) / 128, 256, 0, stream>>>(agg, W1, nullptr, b1, A, N);

    // Layers 2-4: hsb = bf16((A@W)*dinv); A = relu(dinv*(gather) + b)
    k_gemm<128, 128, 0><<<(N + 127) / 128, 256, 0, stream>>>(A, W2, dinv, nullptr, hsb, N);
    k_gather_bf<128, true, true><<<(N * 16 + 255) / 256, 256, 0, stream>>>(
        hsb, rowptr, csr, dinv, b2, A, N);
    k_gemm<128, 128, 0><<<(N + 127) / 128, 256, 0, stream>>>(A, W3, dinv, nullptr, hsb, N);
    k_gather_bf<128, true, true><<<(N * 16 + 255) / 256, 256, 0, stream>>>(
        hsb, rowptr, csr, dinv, b3, A, N);
    k_gemm<128, 128, 0><<<(N + 127) / 128, 256, 0, stream>>>(A, W4, dinv, nullptr, hsb, N);
    k_gather_bf<128, true, true><<<(N * 16 + 255) / 256, 256, 0, stream>>>(
        hsb, rowptr, csr, dinv, b4, A, N);

    // Layer 5: 128 -> 32, no relu
    k_gemm<128, 32, 0><<<(N + 255) / 256, 256, 0, stream>>>(A, Wo, dinv, nullptr, hsb, N);
    k_gather_bf<32, false, true><<<(N * 4 + 255) / 256, 256, 0, stream>>>(
        hsb, rowptr, csr, dinv, bo, A, N);

    // Mean pool + MLP head
    k_pool<<<G, 256, 0, stream>>>(A, batch, gp, N);
    k_mlp<32, 64, true><<<(G * 64 + 255) / 256, 256, 0, stream>>>(gp, M1w, M1b, m1, G);
    k_mlp<64, 16, true><<<(G * 16 + 255) / 256, 256, 0, stream>>>(m1, M2w, M2b, m2, G);
    k_mlp<16, 8, false><<<(G * 8 + 255) / 256, 256, 0, stream>>>(m2, M3w, M3b, (float*)d_out, G);
}

// Round 6
// 626.399 us; speedup vs baseline: 4.9036x; 1.2303x over previous
//
#include <hip/hip_runtime.h>

// ---------------------------------------------------------------------------
// GCN: bucketed CSR-by-dst build + 5 x (MFMA GEMM / gather-aggregate) + pool
// + MLP. Activations/tables bf16 (incoherent rounding, averages out in the
// mean-pool); weights split hi+lo bf16 (2x MFMA) so the coherent weight error
// stays ~4e-6. All accumulation fp32.
// CSR build: histogram -> bucket-major staging -> LDS-cursor scatter (random
// 4B scatter to HBM costs 64B/edge otherwise; measured 100MB writes r2-r4).
// ---------------------------------------------------------------------------

static constexpr int TPB = 256;
static constexpr int NBKT = 128;   // dst buckets: bucket = dst >> 10
static constexpr int NCHK = 256;   // edge chunks

using f32x4  = __attribute__((ext_vector_type(4))) float;
using bf16x8 = __attribute__((ext_vector_type(8))) short;

__device__ __forceinline__ float u2f(unsigned u) { return __uint_as_float(u); }

// fp32 -> bf16 RNE
__device__ __forceinline__ unsigned short bf1(float a) {
    unsigned u = __float_as_uint(a);
    u += 0x7FFFu + ((u >> 16) & 1u);
    return (unsigned short)(u >> 16);
}

// pack two fp32 -> two bf16 (RNE) in one uint
__device__ __forceinline__ unsigned bf2(float a, float b) {
    unsigned ua = __float_as_uint(a);
    unsigned ub = __float_as_uint(b);
    ua += 0x7FFFu + ((ua >> 16) & 1u);
    ub += 0x7FFFu + ((ub >> 16) & 1u);
    return (ua >> 16) | (ub & 0xFFFF0000u);
}

// ------------------------------- CSR build ---------------------------------
__global__ __launch_bounds__(256) void k_hist(const int* __restrict__ dst,
                                              int* __restrict__ histT, int E, int CS) {
    __shared__ int h[NBKT];
    int c = blockIdx.x, t = threadIdx.x;
    if (t < NBKT) h[t] = 0;
    __syncthreads();
    int e0 = c * CS, e1 = min(e0 + CS, E);
    for (int e = e0 + t; e < e1; e += 256)
        atomicAdd(&h[dst[e] >> 10], 1);
    __syncthreads();
    if (t < NBKT) histT[t * NCHK + c] = h[t];
}

__global__ __launch_bounds__(256) void k_scanS(const int* __restrict__ histT,
                                               int* __restrict__ stg) {
    constexpr int TOT = NBKT * NCHK;
    constexpr int PER = TOT / 256;
    __shared__ int s[256];
    int t = threadIdx.x;
    int base = t * PER;
    int sum = 0;
    for (int i = 0; i < PER; ++i) sum += histT[base + i];
    s[t] = sum;
    __syncthreads();
    for (int off = 1; off < 256; off <<= 1) {
        int add = (t >= off) ? s[t - off] : 0;
        __syncthreads();
        s[t] += add;
        __syncthreads();
    }
    int run = (t > 0) ? s[t - 1] : 0;
    for (int i = 0; i < PER; ++i) {
        stg[base + i] = run;
        run += histT[base + i];
    }
}

__global__ __launch_bounds__(256) void k_bucket(const int* __restrict__ src,
                                                const int* __restrict__ dst,
                                                const int* __restrict__ stg,
                                                unsigned* __restrict__ staging,
                                                int E, int CS) {
    __shared__ int cur[NBKT];
    int c = blockIdx.x, t = threadIdx.x;
    if (t < NBKT) cur[t] = stg[t * NCHK + c];
    __syncthreads();
    int e0 = c * CS, e1 = min(e0 + CS, E);
    for (int e = e0 + t; e < e1; e += 256) {
        int d = dst[e];
        int p = atomicAdd(&cur[d >> 10], 1);
        staging[p] = ((unsigned)src[e] << 10) | (unsigned)(d & 1023);
    }
}

__global__ __launch_bounds__(256) void k_deg(const unsigned* __restrict__ staging,
                                             const int* __restrict__ stg,
                                             int* __restrict__ cnt, int E, int n) {
    __shared__ int deg[1024];
    int r = blockIdx.x, t = threadIdx.x;
    for (int i = t; i < 1024; i += 256) deg[i] = 0;
    __syncthreads();
    int s0 = stg[r * NCHK];
    int s1 = (r == NBKT - 1) ? E : stg[(r + 1) * NCHK];
    for (int e = s0 + t; e < s1; e += 256)
        atomicAdd(&deg[staging[e] & 1023u], 1);
    __syncthreads();
    int b = r << 10;
    for (int i = t; i < 1024; i += 256)
        if (b + i < n) cnt[b + i] = deg[i];
}

__global__ void k_scanA(const int* __restrict__ cnt, int* __restrict__ rowptr,
                        int* __restrict__ bsum, int n) {
    __shared__ int s[TPB];
    int t = threadIdx.x;
    int i = blockIdx.x * TPB + t;
    s[t] = (i < n) ? cnt[i] : 0;
    __syncthreads();
    for (int off = 1; off < TPB; off <<= 1) {
        int add = (t >= off) ? s[t - off] : 0;
        __syncthreads();
        s[t] += add;
        __syncthreads();
    }
    if (i < n) rowptr[i + 1] = s[t];
    if (t == TPB - 1) bsum[blockIdx.x] = s[t];
}

__global__ void k_scanB(const int* __restrict__ bsum, int* __restrict__ bscan, int nb) {
    __shared__ int s[512];
    int t = threadIdx.x;
    s[t] = (t < nb) ? bsum[t] : 0;
    __syncthreads();
    for (int off = 1; off < 512; off <<= 1) {
        int add = (t >= off) ? s[t - off] : 0;
        __syncthreads();
        s[t] += add;
        __syncthreads();
    }
    if (t < nb) bscan[t] = (t > 0) ? s[t - 1] : 0;
}

__global__ void k_scanC(int* __restrict__ rowptr, const int* __restrict__ bscan,
                        const int* __restrict__ cnt, float* __restrict__ dinv, int n) {
    int i = blockIdx.x * blockDim.x + threadIdx.x;
    if (i >= n) return;
    rowptr[i + 1] += bscan[i >> 8];
    dinv[i] = rsqrtf((float)cnt[i] + 1.0f);
    if (i == 0) rowptr[0] = 0;
}

__global__ __launch_bounds__(256) void k_fill2(const unsigned* __restrict__ staging,
                                               const int* __restrict__ stg,
                                               const int* __restrict__ rowptr,
                                               int* __restrict__ csr, int E, int n) {
    __shared__ int cur[1024];
    int r = blockIdx.x, t = threadIdx.x;
    int b = r << 10;
    for (int i = t; i < 1024; i += 256)
        cur[i] = (b + i < n) ? rowptr[b + i] : 0;
    __syncthreads();
    int s0 = stg[r * NCHK];
    int s1 = (r == NBKT - 1) ? E : stg[(r + 1) * NCHK];
    for (int e = s0 + t; e < s1; e += 256) {
        unsigned sd = staging[e];
        int p = atomicAdd(&cur[sd & 1023u], 1);
        csr[p] = (int)(sd >> 10);
    }
}

// xs[i,k] = bf16(x[i,k] * dinv[i]); 8 elems/thread
__global__ void k_castx(const float* __restrict__ x, const float* __restrict__ dinv,
                        unsigned short* __restrict__ xs, int n) {
    int gid = blockIdx.x * blockDim.x + threadIdx.x;
    if (gid >= n * 8) return;
    int row = gid >> 3;
    float d = dinv[row];
    const float4* xp = (const float4*)x + (size_t)gid * 2;
    float4 a = xp[0], b = xp[1];
    uint4 o;
    o.x = bf2(a.x * d, a.y * d);
    o.y = bf2(a.z * d, a.w * d);
    o.z = bf2(b.x * d, b.y * d);
    o.w = bf2(b.z * d, b.w * d);
    ((uint4*)xs)[gid] = o;
}

// ---------------------- weight prep: W -> W^T hi/lo bf16 -------------------
// wt layout: [hi: OUT*K][lo: OUT*K], wt[n*K+k] = bf16(W[k][n])
__global__ void k_prepw(const float* __restrict__ W1, const float* __restrict__ W2,
                        const float* __restrict__ W3, const float* __restrict__ W4,
                        const float* __restrict__ Wo,
                        unsigned short* __restrict__ wt1, unsigned short* __restrict__ wt2,
                        unsigned short* __restrict__ wt3, unsigned short* __restrict__ wt4,
                        unsigned short* __restrict__ wto) {
    int b = blockIdx.x, k = threadIdx.x;
    const float* W; unsigned short* wt; int K, OUT, nn;
    if (b < 128)      { W = W1; wt = wt1; K = 64;  OUT = 128; nn = b; }
    else if (b < 256) { W = W2; wt = wt2; K = 128; OUT = 128; nn = b - 128; }
    else if (b < 384) { W = W3; wt = wt3; K = 128; OUT = 128; nn = b - 256; }
    else if (b < 512) { W = W4; wt = wt4; K = 128; OUT = 128; nn = b - 384; }
    else              { W = Wo; wt = wto; K = 128; OUT = 32;  nn = b - 512; }
    if (nn >= OUT || k >= K) return;
    float v = W[(size_t)k * OUT + nn];
    unsigned short hi = bf1(v);
    float fhi = u2f((unsigned)hi << 16);
    unsigned short lo = bf1(v - fhi);
    wt[nn * K + k] = hi;
    wt[OUT * K + nn * K + k] = lo;
}

// ---------------------------- MFMA GEMM ------------------------------------
// out[r][c] = EPI0: bf16(dinv[r] * sum_k A[r][k]*W[k][c])
//             EPI1: bf16(relu(sum_k A[r][k]*W[k][c] + bias[c]))
// A bf16 [n][K]; WT bf16 [2][OUT][K] (hi,lo of W^T). fp32 MFMA accum.
template <int K, int OUT, int EPI>
__global__ __launch_bounds__(256) void k_gemm_mfma(
    const unsigned short* __restrict__ Ain,
    const unsigned short* __restrict__ WT,
    const float* __restrict__ dinv,
    const float* __restrict__ bias,
    unsigned short* __restrict__ out, int n) {
    constexpr int NT = OUT / 16;   // n-tiles
    constexpr int KT = K / 32;     // k-tiles
    constexpr int CH = K / 8;      // 16B chunks per WT row
    __shared__ __align__(16) unsigned short Wl[2 * OUT * K];

    int t = threadIdx.x;
    // stage hi+lo into LDS with XOR-16B swizzle (kills 16-way read conflict)
    {
        const uint4* wg = (const uint4*)WT;
        uint4* wl = (uint4*)Wl;
        for (int i = t; i < 2 * OUT * CH; i += 256) {
            int m = i / (OUT * CH);
            int r = i - m * (OUT * CH);
            int nn = r / CH, g = r - nn * CH;
            wl[m * OUT * CH + nn * CH + (g ^ (nn & 7))] = wg[i];
        }
    }

    int wid = t >> 6, lane = t & 63;
    int lr = lane & 15, lg = lane >> 4;
    int mbase = blockIdx.x * 128 + wid * 32;

    // A fragments: frag layout row = lane&15, k = (lane>>4)*8 + i (contiguous)
    bf16x8 a[2][KT];
#pragma unroll
    for (int mt = 0; mt < 2; ++mt) {
        int row = mbase + mt * 16 + lr;
        row = row < n ? row : n - 1;
        const bf16x8* ap = (const bf16x8*)(Ain + (size_t)row * K);
#pragma unroll
        for (int kt = 0; kt < KT; ++kt)
            a[mt][kt] = ap[kt * 4 + lg];
    }

    __syncthreads();

    f32x4 acc[2][NT] = {};
#pragma unroll
    for (int nt = 0; nt < NT; ++nt) {
        int nn = nt * 16 + lr;
        int swz = nn & 7;
        int rowoff = nn * K;
#pragma unroll
        for (int kt = 0; kt < KT; ++kt) {
            int g = kt * 4 + lg;
            int off = rowoff + ((g ^ swz) * 8);
            bf16x8 bhi = *(const bf16x8*)&Wl[off];
            bf16x8 blo = *(const bf16x8*)&Wl[OUT * K + off];
#pragma unroll
            for (int mt = 0; mt < 2; ++mt) {
                acc[mt][nt] = __builtin_amdgcn_mfma_f32_16x16x32_bf16(
                    a[mt][kt], bhi, acc[mt][nt], 0, 0, 0);
                acc[mt][nt] = __builtin_amdgcn_mfma_f32_16x16x32_bf16(
                    a[mt][kt], blo, acc[mt][nt], 0, 0, 0);
            }
        }
    }

    // C/D layout: col = lane&15, row = (lane>>4)*4 + reg
#pragma unroll
    for (int mt = 0; mt < 2; ++mt) {
        int rbase = mbase + mt * 16 + lg * 4;
        float dv[4];
        if (EPI == 0) {
#pragma unroll
            for (int r = 0; r < 4; ++r)
                dv[r] = (rbase + r < n) ? dinv[rbase + r] : 0.f;
        }
#pragma unroll
        for (int nt = 0; nt < NT; ++nt) {
            int col = nt * 16 + lr;
            float bb = (EPI == 1) ? bias[col] : 0.f;
#pragma unroll
            for (int r = 0; r < 4; ++r) {
                int row = rbase + r;
                if (row < n) {
                    float v = acc[mt][nt][r];
                    if (EPI == 0) v *= dv[r];
                    else v = fmaxf(v + bb, 0.f);
                    out[(size_t)row * OUT + col] = bf1(v);
                }
            }
        }
    }
}

// --------------------------- gather (bf16 table) ---------------------------
__device__ __forceinline__ void addbf(float* acc, uint4 w) {
    acc[0] += u2f(w.x << 16); acc[1] += u2f(w.x & 0xFFFF0000u);
    acc[2] += u2f(w.y << 16); acc[3] += u2f(w.y & 0xFFFF0000u);
    acc[4] += u2f(w.z << 16); acc[5] += u2f(w.z & 0xFFFF0000u);
    acc[6] += u2f(w.w << 16); acc[7] += u2f(w.w & 0xFFFF0000u);
}

// out_i = [relu]( dinv_i * (hs_i + sum_j hs_j) [+ bias] );  bf16 or fp32 out
template <int D, bool RELU, bool HASBIAS, bool OUTBF>
__global__ __launch_bounds__(256) void k_gather_bf(const unsigned short* __restrict__ hsb,
                                                   const int* __restrict__ rowptr,
                                                   const int* __restrict__ csr,
                                                   const float* __restrict__ dinv,
                                                   const float* __restrict__ bias,
                                                   void* __restrict__ outp, int n) {
    constexpr int TPN = D / 8;  // threads per node, 8 bf16 (16B) each
    int gid = blockIdx.x * blockDim.x + threadIdx.x;
    int node = gid / TPN;
    if (node >= n) return;
    int c = gid % TPN;
    const uint4* hb = (const uint4*)hsb;

    float acc[8];
    {
        uint4 v = hb[(size_t)node * TPN + c];
        acc[0] = u2f(v.x << 16); acc[1] = u2f(v.x & 0xFFFF0000u);
        acc[2] = u2f(v.y << 16); acc[3] = u2f(v.y & 0xFFFF0000u);
        acc[4] = u2f(v.z << 16); acc[5] = u2f(v.z & 0xFFFF0000u);
        acc[6] = u2f(v.w << 16); acc[7] = u2f(v.w & 0xFFFF0000u);
    }
    int j0 = rowptr[node], j1 = rowptr[node + 1];
    int j = j0;
    for (; j + 3 < j1; j += 4) {
        int s0 = csr[j], s1 = csr[j + 1], s2 = csr[j + 2], s3 = csr[j + 3];
        uint4 w0 = hb[(size_t)s0 * TPN + c];
        uint4 w1 = hb[(size_t)s1 * TPN + c];
        uint4 w2 = hb[(size_t)s2 * TPN + c];
        uint4 w3 = hb[(size_t)s3 * TPN + c];
        addbf(acc, w0); addbf(acc, w1); addbf(acc, w2); addbf(acc, w3);
    }
    for (; j < j1; ++j) {
        uint4 w0 = hb[(size_t)csr[j] * TPN + c];
        addbf(acc, w0);
    }

    float di = dinv[node];
    float r[8];
    if (HASBIAS) {
        float4 b0 = *(const float4*)&bias[c * 8];
        float4 b1 = *(const float4*)&bias[c * 8 + 4];
        r[0] = di * acc[0] + b0.x; r[1] = di * acc[1] + b0.y;
        r[2] = di * acc[2] + b0.z; r[3] = di * acc[3] + b0.w;
        r[4] = di * acc[4] + b1.x; r[5] = di * acc[5] + b1.y;
        r[6] = di * acc[6] + b1.z; r[7] = di * acc[7] + b1.w;
    } else {
#pragma unroll
        for (int i = 0; i < 8; ++i) r[i] = di * acc[i];
    }
    if (RELU) {
#pragma unroll
        for (int i = 0; i < 8; ++i) r[i] = fmaxf(r[i], 0.f);
    }
    if (OUTBF) {
        uint4 o;
        o.x = bf2(r[0], r[1]); o.y = bf2(r[2], r[3]);
        o.z = bf2(r[4], r[5]); o.w = bf2(r[6], r[7]);
        ((uint4*)outp)[(size_t)node * TPN + c] = o;
    } else {
        float4 o0 = {r[0], r[1], r[2], r[3]};
        float4 o1 = {r[4], r[5], r[6], r[7]};
        float4* op = (float4*)outp + (size_t)node * TPN * 2 + c * 2;
        op[0] = o0;
        op[1] = o1;
    }
}

// ------------------------------ pool + MLP ---------------------------------
__global__ __launch_bounds__(256) void k_pool(const float* __restrict__ h,
                                              const int* __restrict__ batch,
                                              float* __restrict__ g, int n) {
    __shared__ int se[2];
    __shared__ float red[8][32];
    int gi = blockIdx.x;
    int t = threadIdx.x;
    if (t == 0) {
        int lo = 0, hi = n;
        while (lo < hi) { int m = (lo + hi) >> 1; if (batch[m] < gi) lo = m + 1; else hi = m; }
        se[0] = lo;
        lo = 0; hi = n;
        while (lo < hi) { int m = (lo + hi) >> 1; if (batch[m] < gi + 1) lo = m + 1; else hi = m; }
        se[1] = lo;
    }
    __syncthreads();
    int start = se[0], end = se[1];
    int col = t & 31, sub = t >> 5;
    float acc = 0.f;
    for (int i = start + sub; i < end; i += 8)
        acc += h[(size_t)i * 32 + col];
    red[sub][col] = acc;
    __syncthreads();
    if (t < 32) {
        float s = 0.f;
#pragma unroll
        for (int q = 0; q < 8; ++q) s += red[q][t];
        float c = (float)(end - start);
        g[gi * 32 + t] = s / fmaxf(c, 1.0f);
    }
}

template <int K, int O, bool RELU>
__global__ void k_mlp(const float* __restrict__ in, const float* __restrict__ W,
                      const float* __restrict__ b, float* __restrict__ out, int G) {
    int gid = blockIdx.x * blockDim.x + threadIdx.x;
    if (gid >= G * O) return;
    int g = gid / O, j = gid % O;
    float s = b[j];
    for (int k = 0; k < K; ++k) s += in[g * K + k] * W[k * O + j];
    if (RELU) s = fmaxf(s, 0.f);
    out[gid] = s;
}

// ------------------------------- launch ------------------------------------
extern "C" void kernel_launch(void* const* d_in, const int* in_sizes, int n_in,
                              void* d_out, int out_size, void* d_ws, size_t ws_size,
                              hipStream_t stream) {
    const float* x    = (const float*)d_in[0];
    const int*   ei   = (const int*)d_in[1];
    const int*   batch= (const int*)d_in[2];
    const float* W1 = (const float*)d_in[3];  const float* b1 = (const float*)d_in[4];
    const float* W2 = (const float*)d_in[5];  const float* b2 = (const float*)d_in[6];
    const float* W3 = (const float*)d_in[7];  const float* b3 = (const float*)d_in[8];
    const float* W4 = (const float*)d_in[9];  const float* b4 = (const float*)d_in[10];
    const float* Wo = (const float*)d_in[11]; const float* bo = (const float*)d_in[12];
    const float* M1w = (const float*)d_in[13]; const float* M1b = (const float*)d_in[14];
    const float* M2w = (const float*)d_in[15]; const float* M2b = (const float*)d_in[16];
    const float* M3w = (const float*)d_in[17]; const float* M3b = (const float*)d_in[18];

    const int N = in_sizes[0] / 64;   // 100000
    const int E = in_sizes[1] / 2;    // 1600000
    const int G = out_size / 8;       // 64
    const int* src  = ei;
    const int* dstp = ei + E;

    // workspace
    char* w = (char*)d_ws;
    unsigned short* buf1 = (unsigned short*)w; w += (size_t)N * 128 * 2;  // agg/A2/A4; hout fp32
    unsigned short* buf2 = (unsigned short*)w; w += (size_t)N * 128 * 2;  // xs/A1/A3
    unsigned short* hsb  = (unsigned short*)w; w += (size_t)N * 128 * 2;  // tables
    int*      csr     = (int*)w;      w += (size_t)E * 4;
    unsigned* staging = (unsigned*)w; w += (size_t)E * 4;
    int*      histT   = (int*)w;      w += NBKT * NCHK * 4;
    int*      stg     = (int*)w;      w += NBKT * NCHK * 4;
    int*      cnt     = (int*)w;      w += (size_t)N * 4;
    int*      rowptr  = (int*)w;      w += (size_t)(N + 4) * 4;
    int*      bsum    = (int*)w;      w += 4096;
    int*      bscan   = (int*)w;      w += 4096;
    float*    dinv    = (float*)w;    w += (size_t)N * 4;
    unsigned short* wt1 = (unsigned short*)w; w += 2 * 128 * 64 * 2;
    unsigned short* wt2 = (unsigned short*)w; w += 2 * 128 * 128 * 2;
    unsigned short* wt3 = (unsigned short*)w; w += 2 * 128 * 128 * 2;
    unsigned short* wt4 = (unsigned short*)w; w += 2 * 128 * 128 * 2;
    unsigned short* wto = (unsigned short*)w; w += 2 * 32 * 128 * 2;
    float*    gp      = (float*)w;    w += 64 * 32 * 4;
    float*    m1      = (float*)w;    w += 64 * 64 * 4;
    float*    m2      = (float*)w;    w += 64 * 16 * 4;

    const int NB = (N + TPB - 1) / TPB;
    const int CS = (E + NCHK - 1) / NCHK;
    const int GB = (N + 127) / 128;   // MFMA GEMM grid (BM=128)

    // ---- CSR build + weight prep ----
    k_hist<<<NCHK, 256, 0, stream>>>(dstp, histT, E, CS);
    k_prepw<<<544, 128, 0, stream>>>(W1, W2, W3, W4, Wo, wt1, wt2, wt3, wt4, wto);
    k_scanS<<<1, 256, 0, stream>>>(histT, stg);
    k_bucket<<<NCHK, 256, 0, stream>>>(src, dstp, stg, staging, E, CS);
    k_deg<<<NBKT, 256, 0, stream>>>(staging, stg, cnt, E, N);
    k_scanA<<<NB, TPB, 0, stream>>>(cnt, rowptr, bsum, N);
    k_scanB<<<1, 512, 0, stream>>>(bsum, bscan, NB);
    k_scanC<<<NB, TPB, 0, stream>>>(rowptr, bscan, cnt, dinv, N);
    k_fill2<<<NBKT, 256, 0, stream>>>(staging, stg, rowptr, csr, E, N);

    unsigned short* agg = buf1;
    unsigned short* xs  = buf2;

    // Layer 1 (aggregate-first on 64-dim)
    k_castx<<<(N * 8 + 255) / 256, 256, 0, stream>>>(x, dinv, xs, N);
    k_gather_bf<64, false, false, true><<<(N * 8 + 255) / 256, 256, 0, stream>>>(
        xs, rowptr, csr, dinv, nullptr, agg, N);
    k_gemm_mfma<64, 128, 1><<<GB, 256, 0, stream>>>(agg, wt1, nullptr, b1, buf2, N);

    // Layers 2-4
    k_gemm_mfma<128, 128, 0><<<GB, 256, 0, stream>>>(buf2, wt2, dinv, nullptr, hsb, N);
    k_gather_bf<128, true, true, true><<<(N * 16 + 255) / 256, 256, 0, stream>>>(
        hsb, rowptr, csr, dinv, b2, buf1, N);
    k_gemm_mfma<128, 128, 0><<<GB, 256, 0, stream>>>(buf1, wt3, dinv, nullptr, hsb, N);
    k_gather_bf<128, true, true, true><<<(N * 16 + 255) / 256, 256, 0, stream>>>(
        hsb, rowptr, csr, dinv, b3, buf2, N);
    k_gemm_mfma<128, 128, 0><<<GB, 256, 0, stream>>>(buf2, wt4, dinv, nullptr, hsb, N);
    k_gather_bf<128, true, true, true><<<(N * 16 + 255) / 256, 256, 0, stream>>>(
        hsb, rowptr, csr, dinv, b4, buf1, N);

    // Layer 5: 128 -> 32 (fp32 out for pool)
    k_gemm_mfma<128, 32, 0><<<GB, 256, 0, stream>>>(buf1, wto, dinv, nullptr, hsb, N);
    float* hout = (float*)buf2;
    k_gather_bf<32, false, true, false><<<(N * 4 + 255) / 256, 256, 0, stream>>>(
        hsb, rowptr, csr, dinv, bo, hout, N);

    // Mean pool + MLP head
    k_pool<<<G, 256, 0, stream>>>(hout, batch, gp, N);
    k_mlp<32, 64, true><<<(G * 64 + 255) / 256, 256, 0, stream>>>(gp, M1w, M1b, m1, G);
    k_mlp<64, 16, true><<<(G * 16 + 255) / 256, 256, 0, stream>>>(m1, M2w, M2b, m2, G);
    k_mlp<16, 8, false><<<(G * 8 + 255) / 256, 256, 0, stream>>>(m2, M3w, M3b, (float*)d_out, G);
}